// Round 1
// baseline (1988.724 us; speedup 1.0000x reference)
//
#include <hip/hip_runtime.h>
#include <math.h>

#define N_ 64
#define P_ 1024
#define E_ 512
#define H_ 8
#define R_ 64
#define M_ (N_ * P_)   // 65536 rows

#define LOG2F_ 0.69314718055994530942f

// ---------------------------------------------------------------------------
// K1: WS[m, e] = sum_d X[m, d] * Vf[e, d]        (C = X @ V^T)
//   X: (M_, E_) row-major; Vf: (E_, E_) row-major (V[h,r,d] flattened, e=h*R+r)
//   64x64 tile, 256 threads, 4x4 per thread, K-chunk 16.
// ---------------------------------------------------------------------------
__global__ __launch_bounds__(256) void k_gemm_xvt(const float* __restrict__ X,
                                                  const float* __restrict__ Vf,
                                                  float* __restrict__ WS) {
    __shared__ float As[16][68];   // [k][m] ; stride 68 keeps float4 rows 16B-aligned
    __shared__ float Bs[16][68];   // [k][e]
    const int tid = threadIdx.x;
    const int tx = tid & 15;       // col group (e)
    const int ty = tid >> 4;       // row group (m)
    const int m0 = blockIdx.y * 64;
    const int e0 = blockIdx.x * 64;
    float acc[4][4] = {};
    for (int k0 = 0; k0 < E_; k0 += 16) {
        {
            const int row = tid >> 2;          // 0..63
            const int kk  = (tid & 3) * 4;     // 0,4,8,12
            const float4 a = *(const float4*)(X  + (size_t)(m0 + row) * E_ + k0 + kk);
            As[kk + 0][row] = a.x; As[kk + 1][row] = a.y;
            As[kk + 2][row] = a.z; As[kk + 3][row] = a.w;
            const float4 bv = *(const float4*)(Vf + (size_t)(e0 + row) * E_ + k0 + kk);
            Bs[kk + 0][row] = bv.x; Bs[kk + 1][row] = bv.y;
            Bs[kk + 2][row] = bv.z; Bs[kk + 3][row] = bv.w;
        }
        __syncthreads();
#pragma unroll
        for (int k = 0; k < 16; ++k) {
            const float4 a = *(const float4*)&As[k][ty * 4];
            const float4 b = *(const float4*)&Bs[k][tx * 4];
            const float av[4] = {a.x, a.y, a.z, a.w};
            const float bv[4] = {b.x, b.y, b.z, b.w};
#pragma unroll
            for (int i = 0; i < 4; ++i)
#pragma unroll
                for (int j = 0; j < 4; ++j)
                    acc[i][j] = fmaf(av[i], bv[j], acc[i][j]);
        }
        __syncthreads();
    }
#pragma unroll
    for (int i = 0; i < 4; ++i) {
        float4 o = make_float4(acc[i][0], acc[i][1], acc[i][2], acc[i][3]);
        *(float4*)(WS + (size_t)(m0 + ty * 4 + i) * E_ + e0 + tx * 4) = o;
    }
}

// ---------------------------------------------------------------------------
// K2: Y[n, p, h*64+r] = sum_j alpha[h, (j-p)&1023] * WS[n, j, h*64+r]
//   One block per (n, h, p-tile of 64). 64p x 64r tile, K=j over 1024.
// ---------------------------------------------------------------------------
__global__ __launch_bounds__(256) void k_conv(const float* __restrict__ WS,
                                              const float* __restrict__ alpha,
                                              float* __restrict__ Y) {
    const int bid = blockIdx.x;
    const int pt = bid & 15;
    const int h  = (bid >> 4) & 7;
    const int n  = bid >> 7;
    const int p0 = pt * 64;
    const int tid = threadIdx.x;
    const int tx = tid & 15;       // r group
    const int ty = tid >> 4;       // p group
    __shared__ float As[16][68];   // As[k][pp] = alpha[h, (j0+k - p0-pp) & 1023]
    __shared__ float Bs[16][68];   // Bs[k][rr] = WS[n, j0+k, h*64+rr]
    float acc[4][4] = {};
    const float* arow = alpha + h * P_;
    const float* wsn  = WS + (size_t)n * P_ * E_ + h * R_;
    for (int j0 = 0; j0 < P_; j0 += 16) {
        {
            const int pp = tid >> 2;
            const int kk = (tid & 3) * 4;
#pragma unroll
            for (int q = 0; q < 4; ++q) {
                const int jj = j0 + kk + q;
                As[kk + q][pp] = arow[(jj - p0 - pp) & (P_ - 1)];
            }
            const int kk2 = tid >> 4;            // 0..15
            const int rr4 = (tid & 15) * 4;      // 0..60
            const float4 w = *(const float4*)(wsn + (size_t)(j0 + kk2) * E_ + rr4);
            Bs[kk2][rr4 + 0] = w.x; Bs[kk2][rr4 + 1] = w.y;
            Bs[kk2][rr4 + 2] = w.z; Bs[kk2][rr4 + 3] = w.w;
        }
        __syncthreads();
#pragma unroll
        for (int k = 0; k < 16; ++k) {
            const float4 a = *(const float4*)&As[k][ty * 4];
            const float4 b = *(const float4*)&Bs[k][tx * 4];
            const float av[4] = {a.x, a.y, a.z, a.w};
            const float bv[4] = {b.x, b.y, b.z, b.w};
#pragma unroll
            for (int i = 0; i < 4; ++i)
#pragma unroll
                for (int j = 0; j < 4; ++j)
                    acc[i][j] = fmaf(av[i], bv[j], acc[i][j]);
        }
        __syncthreads();
    }
#pragma unroll
    for (int i = 0; i < 4; ++i) {
        float4 o = make_float4(acc[i][0], acc[i][1], acc[i][2], acc[i][3]);
        *(float4*)(Y + (size_t)(n * P_ + p0 + ty * 4 + i) * E_ + h * R_ + tx * 4) = o;
    }
}

// ---------------------------------------------------------------------------
// K3: OUT[m, e'] = log_cosh( sum_e Y[m, e] * W[e, e'] + b[e'] )
//   Same 64x64 tiling; B is read non-transposed (W row-major).
// ---------------------------------------------------------------------------
__global__ __launch_bounds__(256) void k_gemm_w(const float* __restrict__ Y,
                                                const float* __restrict__ W,
                                                const float* __restrict__ b,
                                                float* __restrict__ OUT) {
    __shared__ float As[16][68];   // [k][m]
    __shared__ float Bs[16][68];   // [k][e']
    const int tid = threadIdx.x;
    const int tx = tid & 15;
    const int ty = tid >> 4;
    const int m0 = blockIdx.y * 64;
    const int e0 = blockIdx.x * 64;
    float acc[4][4] = {};
    for (int k0 = 0; k0 < E_; k0 += 16) {
        {
            const int row = tid >> 2;
            const int kk  = (tid & 3) * 4;
            const float4 a = *(const float4*)(Y + (size_t)(m0 + row) * E_ + k0 + kk);
            As[kk + 0][row] = a.x; As[kk + 1][row] = a.y;
            As[kk + 2][row] = a.z; As[kk + 3][row] = a.w;
            const int kk2 = tid >> 4;            // 0..15
            const int jj4 = (tid & 15) * 4;      // 0..60
            const float4 w = *(const float4*)(W + (size_t)(k0 + kk2) * E_ + e0 + jj4);
            Bs[kk2][jj4 + 0] = w.x; Bs[kk2][jj4 + 1] = w.y;
            Bs[kk2][jj4 + 2] = w.z; Bs[kk2][jj4 + 3] = w.w;
        }
        __syncthreads();
#pragma unroll
        for (int k = 0; k < 16; ++k) {
            const float4 a = *(const float4*)&As[k][ty * 4];
            const float4 b2 = *(const float4*)&Bs[k][tx * 4];
            const float av[4] = {a.x, a.y, a.z, a.w};
            const float bv[4] = {b2.x, b2.y, b2.z, b2.w};
#pragma unroll
            for (int i = 0; i < 4; ++i)
#pragma unroll
                for (int j = 0; j < 4; ++j)
                    acc[i][j] = fmaf(av[i], bv[j], acc[i][j]);
        }
        __syncthreads();
    }
    const float4 bb = *(const float4*)(b + e0 + tx * 4);
    const float bvv[4] = {bb.x, bb.y, bb.z, bb.w};
#pragma unroll
    for (int i = 0; i < 4; ++i) {
        float o[4];
#pragma unroll
        for (int j = 0; j < 4; ++j) {
            const float v  = acc[i][j] + bvv[j];
            const float ax = fabsf(v);
            o[j] = ax + log1pf(expf(-2.0f * ax)) - LOG2F_;
        }
        float4 ov = make_float4(o[0], o[1], o[2], o[3]);
        *(float4*)(OUT + (size_t)(m0 + ty * 4 + i) * E_ + e0 + tx * 4) = ov;
    }
}

// ---------------------------------------------------------------------------
// Buffer plan (avoids in-place hazards with a single 134 MB scratch):
//   K1: ws -> d_out      (scratch use of the output buffer)
//   K2: reads d_out(ws), writes y -> d_ws
//   K3: reads d_ws(y),  writes final -> d_out
// ---------------------------------------------------------------------------
extern "C" void kernel_launch(void* const* d_in, const int* in_sizes, int n_in,
                              void* d_out, int out_size, void* d_ws, size_t ws_size,
                              hipStream_t stream) {
    const float* x     = (const float*)d_in[0];   // (N, P, E)
    const float* alpha = (const float*)d_in[1];   // (H, P)
    const float* V     = (const float*)d_in[2];   // (H, R, E) == (E_, E_) flat
    const float* W     = (const float*)d_in[3];   // (E, E)
    const float* b     = (const float*)d_in[4];   // (E,)
    float* out = (float*)d_out;                   // (N, P, E)
    float* ws  = (float*)d_out;                   // stage-1 scratch lives in d_out
    float* y   = (float*)d_ws;                    // needs N_*P_*E_*4 = 134217728 B

    dim3 blk(256);
    dim3 grid1(E_ / 64, M_ / 64);                 // (8, 1024)
    k_gemm_xvt<<<grid1, blk, 0, stream>>>(x, V, ws);

    dim3 grid2(N_ * H_ * (P_ / 64));              // 64*8*16 = 8192
    k_conv<<<grid2, blk, 0, stream>>>(ws, alpha, y);

    dim3 grid3(E_ / 64, M_ / 64);
    k_gemm_w<<<grid3, blk, 0, stream>>>(y, W, b, out);
}

// Round 2
// 582.347 us; speedup vs baseline: 3.4150x; 3.4150x over previous
//
#include <hip/hip_runtime.h>
#include <math.h>

typedef float f32x4 __attribute__((ext_vector_type(4)));
typedef __bf16 bf16x8 __attribute__((ext_vector_type(8)));
typedef unsigned short u16x8 __attribute__((ext_vector_type(8)));
typedef unsigned short u16x4 __attribute__((ext_vector_type(4)));

#define LN2F_ 0.69314718055994530942f

__device__ inline unsigned short f2bf(float f) {
    unsigned u = __builtin_bit_cast(unsigned, f);
    u += 0x7fffu + ((u >> 16) & 1u);
    return (unsigned short)(u >> 16);
}

__device__ inline bf16x8 ld_frag(const unsigned short* p) {
    return __builtin_bit_cast(bf16x8, *(const u16x8*)p);
}

// ---------------------------------------------------------------------------
// fp32 -> bf16 bulk convert (n4 = count/4)
// ---------------------------------------------------------------------------
__global__ __launch_bounds__(256) void k_cvt(const float* __restrict__ in,
                                             unsigned short* __restrict__ out, int n4) {
    int i = blockIdx.x * 256 + threadIdx.x;
    if (i >= n4) return;
    float4 v = ((const float4*)in)[i];
    u16x4 o = { f2bf(v.x), f2bf(v.y), f2bf(v.z), f2bf(v.w) };
    *(u16x4*)(out + (size_t)i * 4) = o;
}

// ---------------------------------------------------------------------------
// am[h][p][j] = bf16(alpha[h][(j - p) & 1023]) ; 1 thread = 8 j's
// ---------------------------------------------------------------------------
__global__ __launch_bounds__(256) void k_build_am(const float* __restrict__ alpha,
                                                  unsigned short* __restrict__ am) {
    int t = blockIdx.x * 256 + threadIdx.x;          // 0 .. 1048575
    int j8 = (t & 127) << 3;
    int p  = (t >> 7) & 1023;
    int h  = t >> 17;
    const float* ar = alpha + (h << 10);
    u16x8 o;
#pragma unroll
    for (int q = 0; q < 8; ++q) o[q] = f2bf(ar[(j8 + q - p) & 1023]);
    *(u16x8*)(am + ((size_t)t << 3)) = o;
}

// ---------------------------------------------------------------------------
// WT[e'][e] = bf16(W[e][e'])
// ---------------------------------------------------------------------------
__global__ __launch_bounds__(256) void k_build_wt(const float* __restrict__ W,
                                                  unsigned short* __restrict__ WT) {
    int t = blockIdx.x * 256 + threadIdx.x;          // 0 .. 262143
    int e1 = t >> 9, e = t & 511;
    WT[t] = f2bf(W[e * 512 + e1]);
}

// ---------------------------------------------------------------------------
// K1: wsT[n][e][p] = sum_d xb[(n,p)][d] * Vb[e][d]
//   BM=128 (m=(n,p)), BN=128 (e), BK=32. 4 waves, each 64x64 (4x4 MFMA tiles).
// ---------------------------------------------------------------------------
__global__ __launch_bounds__(256) void k_gemm1(const unsigned short* __restrict__ A,
                                               const unsigned short* __restrict__ B,
                                               unsigned short* __restrict__ wsT) {
    __shared__ __align__(16) unsigned short As[128 * 40];
    __shared__ __align__(16) unsigned short Bs[128 * 40];
    const int tid = threadIdx.x;
    const int m0 = blockIdx.y * 128;
    const int e0 = blockIdx.x * 128;
    const int w = tid >> 6, lane = tid & 63, ml = lane & 15, quad = lane >> 4;
    const int wr = w >> 1, wc = w & 1;
    const int row_s = tid >> 2, seg_s = tid & 3;
    f32x4 acc[4][4] = {};
    for (int k0 = 0; k0 < 512; k0 += 32) {
        u16x8 ra[2], rb[2];
#pragma unroll
        for (int s = 0; s < 2; ++s) {
            int row = row_s + s * 64;
            ra[s] = *(const u16x8*)(A + (size_t)(m0 + row) * 512 + k0 + seg_s * 8);
            rb[s] = *(const u16x8*)(B + (size_t)(e0 + row) * 512 + k0 + seg_s * 8);
        }
        __syncthreads();
#pragma unroll
        for (int s = 0; s < 2; ++s) {
            int row = row_s + s * 64;
            *(u16x8*)(As + row * 40 + seg_s * 8) = ra[s];
            *(u16x8*)(Bs + row * 40 + seg_s * 8) = rb[s];
        }
        __syncthreads();
        bf16x8 af[4], bfr[4];
#pragma unroll
        for (int i = 0; i < 4; ++i) {
            af[i]  = ld_frag(As + (wr * 64 + i * 16 + ml) * 40 + quad * 8);
            bfr[i] = ld_frag(Bs + (wc * 64 + i * 16 + ml) * 40 + quad * 8);
        }
#pragma unroll
        for (int i = 0; i < 4; ++i)
#pragma unroll
            for (int j = 0; j < 4; ++j)
                acc[i][j] = __builtin_amdgcn_mfma_f32_16x16x32_bf16(af[i], bfr[j], acc[i][j], 0, 0, 0);
    }
    const int n = m0 >> 10;
    const int pblk = m0 & 1023;
#pragma unroll
    for (int i = 0; i < 4; ++i) {
        int p = pblk + wr * 64 + i * 16 + quad * 4;
#pragma unroll
        for (int j = 0; j < 4; ++j) {
            int e = e0 + wc * 64 + j * 16 + ml;
            u16x4 o = { f2bf(acc[i][j][0]), f2bf(acc[i][j][1]),
                        f2bf(acc[i][j][2]), f2bf(acc[i][j][3]) };
            *(u16x4*)(wsT + ((size_t)n * 512 + e) * 1024 + p) = o;
        }
    }
}

// ---------------------------------------------------------------------------
// K2: y[n][p][h*64+r] = sum_j am[h][p][j] * wsT[n][h*64+r][j]
//   D[m=r][n=p]: BM=64 (r), BN=128 (p), BK=32. 4 waves, each 32x64 (2x4 tiles).
// ---------------------------------------------------------------------------
__global__ __launch_bounds__(256) void k_gemm2(const unsigned short* __restrict__ wsT,
                                               const unsigned short* __restrict__ am,
                                               unsigned short* __restrict__ y) {
    __shared__ __align__(16) unsigned short As[64 * 40];
    __shared__ __align__(16) unsigned short Bs[128 * 40];
    const int tid = threadIdx.x;
    const int p0 = blockIdx.x * 128;
    const int h  = blockIdx.y;
    const int n  = blockIdx.z;
    const int w = tid >> 6, lane = tid & 63, ml = lane & 15, quad = lane >> 4;
    const int wr = w >> 1, wc = w & 1;
    const int row_s = tid >> 2, seg_s = tid & 3;
    const unsigned short* Abase = wsT + (size_t)n * 524288 + (size_t)(h * 64) * 1024;
    const unsigned short* Bbase = am + ((size_t)h * 1024 + p0) * 1024;
    f32x4 acc[2][4] = {};
    for (int j0 = 0; j0 < 1024; j0 += 32) {
        u16x8 ra  = *(const u16x8*)(Abase + (size_t)row_s * 1024 + j0 + seg_s * 8);
        u16x8 rb0 = *(const u16x8*)(Bbase + (size_t)row_s * 1024 + j0 + seg_s * 8);
        u16x8 rb1 = *(const u16x8*)(Bbase + (size_t)(row_s + 64) * 1024 + j0 + seg_s * 8);
        __syncthreads();
        *(u16x8*)(As + row_s * 40 + seg_s * 8) = ra;
        *(u16x8*)(Bs + row_s * 40 + seg_s * 8) = rb0;
        *(u16x8*)(Bs + (row_s + 64) * 40 + seg_s * 8) = rb1;
        __syncthreads();
        bf16x8 af[2], bfr[4];
#pragma unroll
        for (int mt = 0; mt < 2; ++mt)
            af[mt] = ld_frag(As + (wr * 32 + mt * 16 + ml) * 40 + quad * 8);
#pragma unroll
        for (int nt = 0; nt < 4; ++nt)
            bfr[nt] = ld_frag(Bs + (wc * 64 + nt * 16 + ml) * 40 + quad * 8);
#pragma unroll
        for (int mt = 0; mt < 2; ++mt)
#pragma unroll
            for (int nt = 0; nt < 4; ++nt)
                acc[mt][nt] = __builtin_amdgcn_mfma_f32_16x16x32_bf16(af[mt], bfr[nt], acc[mt][nt], 0, 0, 0);
    }
#pragma unroll
    for (int mt = 0; mt < 2; ++mt) {
        int r0 = wr * 32 + mt * 16 + quad * 4;
#pragma unroll
        for (int nt = 0; nt < 4; ++nt) {
            int p = p0 + wc * 64 + nt * 16 + ml;
            u16x4 o = { f2bf(acc[mt][nt][0]), f2bf(acc[mt][nt][1]),
                        f2bf(acc[mt][nt][2]), f2bf(acc[mt][nt][3]) };
            *(u16x4*)(y + ((size_t)n * 1024 + p) * 512 + h * 64 + r0) = o;
        }
    }
}

// ---------------------------------------------------------------------------
// K3: out[m][e'] = log_cosh( sum_e y[m][e] * WT[e'][e] + b[e'] )  (fp32 out)
// ---------------------------------------------------------------------------
__global__ __launch_bounds__(256) void k_gemm3(const unsigned short* __restrict__ A,
                                               const unsigned short* __restrict__ B,
                                               const float* __restrict__ bias,
                                               float* __restrict__ out) {
    __shared__ __align__(16) unsigned short As[128 * 40];
    __shared__ __align__(16) unsigned short Bs[128 * 40];
    const int tid = threadIdx.x;
    const int m0 = blockIdx.y * 128;
    const int e0 = blockIdx.x * 128;
    const int w = tid >> 6, lane = tid & 63, ml = lane & 15, quad = lane >> 4;
    const int wr = w >> 1, wc = w & 1;
    const int row_s = tid >> 2, seg_s = tid & 3;
    f32x4 acc[4][4] = {};
    for (int k0 = 0; k0 < 512; k0 += 32) {
        u16x8 ra[2], rb[2];
#pragma unroll
        for (int s = 0; s < 2; ++s) {
            int row = row_s + s * 64;
            ra[s] = *(const u16x8*)(A + (size_t)(m0 + row) * 512 + k0 + seg_s * 8);
            rb[s] = *(const u16x8*)(B + (size_t)(e0 + row) * 512 + k0 + seg_s * 8);
        }
        __syncthreads();
#pragma unroll
        for (int s = 0; s < 2; ++s) {
            int row = row_s + s * 64;
            *(u16x8*)(As + row * 40 + seg_s * 8) = ra[s];
            *(u16x8*)(Bs + row * 40 + seg_s * 8) = rb[s];
        }
        __syncthreads();
        bf16x8 af[4], bfr[4];
#pragma unroll
        for (int i = 0; i < 4; ++i) {
            af[i]  = ld_frag(As + (wr * 64 + i * 16 + ml) * 40 + quad * 8);
            bfr[i] = ld_frag(Bs + (wc * 64 + i * 16 + ml) * 40 + quad * 8);
        }
#pragma unroll
        for (int i = 0; i < 4; ++i)
#pragma unroll
            for (int j = 0; j < 4; ++j)
                acc[i][j] = __builtin_amdgcn_mfma_f32_16x16x32_bf16(af[i], bfr[j], acc[i][j], 0, 0, 0);
    }
#pragma unroll
    for (int j = 0; j < 4; ++j) {
        int e = e0 + wc * 64 + j * 16 + ml;
        float bv = bias[e];
#pragma unroll
        for (int i = 0; i < 4; ++i) {
            int mg = m0 + wr * 64 + i * 16 + quad * 4;
#pragma unroll
            for (int r = 0; r < 4; ++r) {
                float v  = acc[i][j][r] + bv;
                float ax = fabsf(v);
                out[(size_t)(mg + r) * 512 + e] = ax + log1pf(expf(-2.0f * ax)) - LN2F_;
            }
        }
    }
}

// ---------------------------------------------------------------------------
// Buffer plan:
//   d_out (134 MB): [0,67M) xb | [67,83M) am | [83,83.5M) Vb  -> K3 overwrites all
//   d_ws  (134 MB): [0,67M) wsT (dead after K2; first 0.5 MB reused for WT) |
//                   [67,134M) y
// Order: cvt_x, cvt_v, build_am -> K1 -> K2 -> build_wt -> K3
// ---------------------------------------------------------------------------
extern "C" void kernel_launch(void* const* d_in, const int* in_sizes, int n_in,
                              void* d_out, int out_size, void* d_ws, size_t ws_size,
                              hipStream_t stream) {
    const float* x     = (const float*)d_in[0];
    const float* alpha = (const float*)d_in[1];
    const float* V     = (const float*)d_in[2];
    const float* W     = (const float*)d_in[3];
    const float* b     = (const float*)d_in[4];

    unsigned short* xb  = (unsigned short*)d_out;
    unsigned short* am  = xb + 33554432;           // 67 MB offset
    unsigned short* Vb  = am + 8388608;            // 83 MB offset
    unsigned short* wsT = (unsigned short*)d_ws;
    unsigned short* y   = wsT + 33554432;
    unsigned short* WT  = wsT;                     // reuse wsT region after K2
    float* out = (float*)d_out;

    k_cvt<<<32768, 256, 0, stream>>>(x, xb, 8388608);
    k_cvt<<<256, 256, 0, stream>>>(V, Vb, 65536);
    k_build_am<<<4096, 256, 0, stream>>>(alpha, am);

    k_gemm1<<<dim3(4, 512), 256, 0, stream>>>(xb, Vb, wsT);
    k_gemm2<<<dim3(8, 8, 64), 256, 0, stream>>>(wsT, am, y);
    k_build_wt<<<1024, 256, 0, stream>>>(W, WT);
    k_gemm3<<<dim3(4, 512), 256, 0, stream>>>(y, WT, b, out);
}

// Round 3
// 525.264 us; speedup vs baseline: 3.7861x; 1.1087x over previous
//
#include <hip/hip_runtime.h>
#include <math.h>

typedef float f32x4 __attribute__((ext_vector_type(4)));
typedef __bf16 bf16x8 __attribute__((ext_vector_type(8)));
typedef unsigned short u16x8 __attribute__((ext_vector_type(8)));
typedef unsigned short u16x4 __attribute__((ext_vector_type(4)));

#define LN2F_ 0.69314718055994530942f

__device__ inline unsigned short f2bf(float f) {
    unsigned u = __builtin_bit_cast(unsigned, f);
    u += 0x7fffu + ((u >> 16) & 1u);
    return (unsigned short)(u >> 16);
}

// ---------------------------------------------------------------------------
// Swizzled LDS tile: tile = R rows x 32 k (bf16), stored as 16B blocks.
//   addr(row, c) = (row>>4)*512 + ((c<<4) + ((row&15) ^ (c<<1))) * 8   [shorts]
// Verified by enumeration: every 8-lane phase of the staging writes AND the
// fragment reads covers all 32 banks exactly once -> conflict-free, and
// fragment reads are lane-contiguous 1 KiB per wave.
// ---------------------------------------------------------------------------
__device__ inline void stage_st(unsigned short* Ls, int row, int c, u16x8 v) {
    *(u16x8*)(Ls + (row >> 4) * 512 + (((c) << 4) + ((row & 15) ^ ((c) << 1))) * 8) = v;
}
__device__ inline bf16x8 frag_ld(const unsigned short* Ls, int s, int ml, int q) {
    return __builtin_bit_cast(bf16x8,
        *(const u16x8*)(Ls + s * 512 + (((q) << 4) + (ml ^ ((q) << 1))) * 8));
}

// ---------------------------------------------------------------------------
// fp32 -> bf16 bulk convert (used only for V, tiny)
// ---------------------------------------------------------------------------
__global__ __launch_bounds__(256) void k_cvt(const float* __restrict__ in,
                                             unsigned short* __restrict__ out, int n4) {
    int i = blockIdx.x * 256 + threadIdx.x;
    if (i >= n4) return;
    float4 v = ((const float4*)in)[i];
    u16x4 o = { f2bf(v.x), f2bf(v.y), f2bf(v.z), f2bf(v.w) };
    *(u16x4*)(out + (size_t)i * 4) = o;
}

// am[h][p][j] = bf16(alpha[h][(j - p) & 1023])
__global__ __launch_bounds__(256) void k_build_am(const float* __restrict__ alpha,
                                                  unsigned short* __restrict__ am) {
    int t = blockIdx.x * 256 + threadIdx.x;          // 0 .. 1048575
    int j8 = (t & 127) << 3;
    int p  = (t >> 7) & 1023;
    int h  = t >> 17;
    const float* ar = alpha + (h << 10);
    u16x8 o;
#pragma unroll
    for (int q = 0; q < 8; ++q) o[q] = f2bf(ar[(j8 + q - p) & 1023]);
    *(u16x8*)(am + ((size_t)t << 3)) = o;
}

// WT[e'][e] = bf16(W[e][e'])
__global__ __launch_bounds__(256) void k_build_wt(const float* __restrict__ W,
                                                  unsigned short* __restrict__ WT) {
    int t = blockIdx.x * 256 + threadIdx.x;          // 0 .. 262143
    int e1 = t >> 9, e = t & 511;
    WT[t] = f2bf(W[e * 512 + e1]);
}

// ---------------------------------------------------------------------------
// K1: wsT[n][e][p] = sum_d x[(n,p)][d] * Vb[e][d]   (x fp32, converted in-kernel)
//   BM=128, BN=128, BK=32; 4 waves x (64x64).
// ---------------------------------------------------------------------------
__global__ __launch_bounds__(256) void k_gemm1(const float* __restrict__ X,
                                               const unsigned short* __restrict__ B,
                                               unsigned short* __restrict__ wsT) {
    __shared__ __align__(16) unsigned short As[128 * 32];
    __shared__ __align__(16) unsigned short Bs[128 * 32];
    const int tid = threadIdx.x;
    const int m0 = blockIdx.y * 128;
    const int e0 = blockIdx.x * 128;
    const int w = tid >> 6, lane = tid & 63, ml = lane & 15, quad = lane >> 4;
    const int wr = w >> 1, wc = w & 1;
    const int srow = tid >> 1, shalf = tid & 1;      // 128 rows, 2 threads/row
    f32x4 acc[4][4] = {};
    for (int k0 = 0; k0 < 512; k0 += 32) {
        const float* ap = X + (size_t)(m0 + srow) * 512 + k0 + shalf * 16;
        float4 a0 = ((const float4*)ap)[0];
        float4 a1 = ((const float4*)ap)[1];
        float4 a2 = ((const float4*)ap)[2];
        float4 a3 = ((const float4*)ap)[3];
        const unsigned short* bp = B + (size_t)(e0 + srow) * 512 + k0 + shalf * 16;
        u16x8 rb0 = *(const u16x8*)bp;
        u16x8 rb1 = *(const u16x8*)(bp + 8);
        __syncthreads();
        u16x8 pa0 = { f2bf(a0.x), f2bf(a0.y), f2bf(a0.z), f2bf(a0.w),
                      f2bf(a1.x), f2bf(a1.y), f2bf(a1.z), f2bf(a1.w) };
        u16x8 pa1 = { f2bf(a2.x), f2bf(a2.y), f2bf(a2.z), f2bf(a2.w),
                      f2bf(a3.x), f2bf(a3.y), f2bf(a3.z), f2bf(a3.w) };
        stage_st(As, srow, shalf * 2 + 0, pa0);
        stage_st(As, srow, shalf * 2 + 1, pa1);
        stage_st(Bs, srow, shalf * 2 + 0, rb0);
        stage_st(Bs, srow, shalf * 2 + 1, rb1);
        __syncthreads();
        bf16x8 af[4], bfr[4];
#pragma unroll
        for (int i = 0; i < 4; ++i) {
            af[i]  = frag_ld(As, wr * 4 + i, ml, quad);
            bfr[i] = frag_ld(Bs, wc * 4 + i, ml, quad);
        }
#pragma unroll
        for (int i = 0; i < 4; ++i)
#pragma unroll
            for (int j = 0; j < 4; ++j)
                acc[i][j] = __builtin_amdgcn_mfma_f32_16x16x32_bf16(af[i], bfr[j], acc[i][j], 0, 0, 0);
    }
    const int n = m0 >> 10;
    const int pblk = m0 & 1023;
#pragma unroll
    for (int i = 0; i < 4; ++i) {
        int p = pblk + wr * 64 + i * 16 + quad * 4;
#pragma unroll
        for (int j = 0; j < 4; ++j) {
            int e = e0 + wc * 64 + j * 16 + ml;
            u16x4 o = { f2bf(acc[i][j][0]), f2bf(acc[i][j][1]),
                        f2bf(acc[i][j][2]), f2bf(acc[i][j][3]) };
            *(u16x4*)(wsT + ((size_t)n * 512 + e) * 1024 + p) = o;
        }
    }
}

// ---------------------------------------------------------------------------
// K2: y[n][p][h*64+r] = sum_j am[h][p][j] * wsT[n][h*64+r][j]
//   BM=64 (r), BN=128 (p), BK=32; 4 waves x (32x64).
// ---------------------------------------------------------------------------
__global__ __launch_bounds__(256) void k_gemm2(const unsigned short* __restrict__ wsT,
                                               const unsigned short* __restrict__ am,
                                               unsigned short* __restrict__ y) {
    __shared__ __align__(16) unsigned short As[64 * 32];
    __shared__ __align__(16) unsigned short Bs[128 * 32];
    const int tid = threadIdx.x;
    const int p0 = blockIdx.x * 128;
    const int h  = blockIdx.y;
    const int n  = blockIdx.z;
    const int w = tid >> 6, lane = tid & 63, ml = lane & 15, quad = lane >> 4;
    const int wr = w >> 1, wc = w & 1;
    const int arow = tid >> 2, ac = tid & 3;         // 64 rows, 4 threads/row
    const int brow = tid >> 1, bhalf = tid & 1;      // 128 rows, 2 threads/row
    const unsigned short* Abase = wsT + (size_t)n * 524288 + (size_t)(h * 64) * 1024;
    const unsigned short* Bbase = am + ((size_t)h * 1024 + p0) * 1024;
    f32x4 acc[2][4] = {};
    for (int j0 = 0; j0 < 1024; j0 += 32) {
        u16x8 ra  = *(const u16x8*)(Abase + (size_t)arow * 1024 + j0 + ac * 8);
        const unsigned short* bp = Bbase + (size_t)brow * 1024 + j0 + bhalf * 16;
        u16x8 rb0 = *(const u16x8*)bp;
        u16x8 rb1 = *(const u16x8*)(bp + 8);
        __syncthreads();
        stage_st(As, arow, ac, ra);
        stage_st(Bs, brow, bhalf * 2 + 0, rb0);
        stage_st(Bs, brow, bhalf * 2 + 1, rb1);
        __syncthreads();
        bf16x8 af[2], bfr[4];
#pragma unroll
        for (int mt = 0; mt < 2; ++mt)
            af[mt] = frag_ld(As, wr * 2 + mt, ml, quad);
#pragma unroll
        for (int nt = 0; nt < 4; ++nt)
            bfr[nt] = frag_ld(Bs, wc * 4 + nt, ml, quad);
#pragma unroll
        for (int mt = 0; mt < 2; ++mt)
#pragma unroll
            for (int nt = 0; nt < 4; ++nt)
                acc[mt][nt] = __builtin_amdgcn_mfma_f32_16x16x32_bf16(af[mt], bfr[nt], acc[mt][nt], 0, 0, 0);
    }
#pragma unroll
    for (int mt = 0; mt < 2; ++mt) {
        int r0 = wr * 32 + mt * 16 + quad * 4;
#pragma unroll
        for (int nt = 0; nt < 4; ++nt) {
            int p = p0 + wc * 64 + nt * 16 + ml;
            u16x4 o = { f2bf(acc[mt][nt][0]), f2bf(acc[mt][nt][1]),
                        f2bf(acc[mt][nt][2]), f2bf(acc[mt][nt][3]) };
            *(u16x4*)(y + ((size_t)n * 1024 + p) * 512 + h * 64 + r0) = o;
        }
    }
}

// ---------------------------------------------------------------------------
// K3: out[m][e'] = log_cosh( sum_e y[m][e] * WT[e'][e] + b[e'] )  (fp32 out)
//   Fast epilogue: __expf/__logf (single-instruction transcendentals).
// ---------------------------------------------------------------------------
__global__ __launch_bounds__(256) void k_gemm3(const unsigned short* __restrict__ A,
                                               const unsigned short* __restrict__ B,
                                               const float* __restrict__ bias,
                                               float* __restrict__ out) {
    __shared__ __align__(16) unsigned short As[128 * 32];
    __shared__ __align__(16) unsigned short Bs[128 * 32];
    const int tid = threadIdx.x;
    const int m0 = blockIdx.y * 128;
    const int e0 = blockIdx.x * 128;
    const int w = tid >> 6, lane = tid & 63, ml = lane & 15, quad = lane >> 4;
    const int wr = w >> 1, wc = w & 1;
    const int srow = tid >> 1, shalf = tid & 1;
    f32x4 acc[4][4] = {};
    for (int k0 = 0; k0 < 512; k0 += 32) {
        const unsigned short* ap = A + (size_t)(m0 + srow) * 512 + k0 + shalf * 16;
        u16x8 ra0 = *(const u16x8*)ap;
        u16x8 ra1 = *(const u16x8*)(ap + 8);
        const unsigned short* bp = B + (size_t)(e0 + srow) * 512 + k0 + shalf * 16;
        u16x8 rb0 = *(const u16x8*)bp;
        u16x8 rb1 = *(const u16x8*)(bp + 8);
        __syncthreads();
        stage_st(As, srow, shalf * 2 + 0, ra0);
        stage_st(As, srow, shalf * 2 + 1, ra1);
        stage_st(Bs, srow, shalf * 2 + 0, rb0);
        stage_st(Bs, srow, shalf * 2 + 1, rb1);
        __syncthreads();
        bf16x8 af[4], bfr[4];
#pragma unroll
        for (int i = 0; i < 4; ++i) {
            af[i]  = frag_ld(As, wr * 4 + i, ml, quad);
            bfr[i] = frag_ld(Bs, wc * 4 + i, ml, quad);
        }
#pragma unroll
        for (int i = 0; i < 4; ++i)
#pragma unroll
            for (int j = 0; j < 4; ++j)
                acc[i][j] = __builtin_amdgcn_mfma_f32_16x16x32_bf16(af[i], bfr[j], acc[i][j], 0, 0, 0);
    }
#pragma unroll
    for (int j = 0; j < 4; ++j) {
        int e = e0 + wc * 64 + j * 16 + ml;
        float bv = bias[e];
#pragma unroll
        for (int i = 0; i < 4; ++i) {
            int mg = m0 + wr * 64 + i * 16 + quad * 4;
#pragma unroll
            for (int r = 0; r < 4; ++r) {
                float v  = acc[i][j][r] + bv;
                float ax = fabsf(v);
                float t  = __expf(-2.0f * ax);
                out[(size_t)(mg + r) * 512 + e] = ax + __logf(1.0f + t) - LN2F_;
            }
        }
    }
}

// ---------------------------------------------------------------------------
// Buffers:
//   d_out: [am 16 MB | Vb 0.5 MB]  (consumed before K3 overwrites d_out)
//   d_ws : [wsT 67 MB (reused for WT after K2) | y 67 MB]
// Order: cvt(V), build_am -> K1 -> K2 -> build_wt -> K3
// ---------------------------------------------------------------------------
extern "C" void kernel_launch(void* const* d_in, const int* in_sizes, int n_in,
                              void* d_out, int out_size, void* d_ws, size_t ws_size,
                              hipStream_t stream) {
    const float* x     = (const float*)d_in[0];
    const float* alpha = (const float*)d_in[1];
    const float* V     = (const float*)d_in[2];
    const float* W     = (const float*)d_in[3];
    const float* b     = (const float*)d_in[4];

    unsigned short* am  = (unsigned short*)d_out;
    unsigned short* Vb  = am + 8388608;
    unsigned short* wsT = (unsigned short*)d_ws;
    unsigned short* y   = wsT + 33554432;
    unsigned short* WT  = wsT;
    float* out = (float*)d_out;

    k_cvt<<<256, 256, 0, stream>>>(V, Vb, 65536);
    k_build_am<<<4096, 256, 0, stream>>>(alpha, am);

    k_gemm1<<<dim3(4, 512), 256, 0, stream>>>(x, Vb, wsT);
    k_gemm2<<<dim3(8, 8, 64), 256, 0, stream>>>(wsT, am, y);
    k_build_wt<<<1024, 256, 0, stream>>>(W, WT);
    k_gemm3<<<dim3(4, 512), 256, 0, stream>>>(y, WT, b, out);
}